// Round 9
// baseline (1431.409 us; speedup 1.0000x reference)
//
#include <hip/hip_runtime.h>
#include <hip/hip_bf16.h>
#include <math.h>

// Problem constants
#define B_  64
#define W_  128
#define L_  32
#define V_  128
#define E_  128
#define H_  256
#define G4_ 1024      // 4*H
#define NW  8192      // B*W words
#define KS_ 8         // MFMA k-steps: h only (K=256); eproj added via bf16 gather
#define KPAD 264      // padded LDS row (bf16): 256 used + 8 pad (528B = 33*16B, odd)
#define M_  64        // words per block

typedef short s8v  __attribute__((ext_vector_type(8)));  // 8 bf16 (4 VGPR)
typedef float f4v  __attribute__((ext_vector_type(4)));

static __device__ __forceinline__ float b2f(unsigned short u) {
  return __uint_as_float(((unsigned int)u) << 16);
}

// ---------------------------------------------------------------------------
// K1: ep4[dir][v][col][gate] = bf16( dot(emb[v], Wih_dir[gate*256+col]) + biases )
// gate-last ushort4 layout: one 8B load gives all 4 gate pre-activations.
// ---------------------------------------------------------------------------
__global__ __launch_bounds__(256) void k_embproj(
    const float* __restrict__ emb,
    const float* __restrict__ Wih_f, const float* __restrict__ bih_f, const float* __restrict__ bhh_f,
    const float* __restrict__ Wih_b, const float* __restrict__ bih_b, const float* __restrict__ bhh_b,
    unsigned short* __restrict__ ep4) {
  int v   = blockIdx.x & (V_ - 1);
  int dir = blockIdx.x >> 7;
  const float* Wih = dir ? Wih_b : Wih_f;
  const float* b1  = dir ? bih_b : bih_f;
  const float* b2  = dir ? bhh_b : bhh_f;
  __shared__ float es[E_];
  if (threadIdx.x < E_) es[threadIdx.x] = emb[v * E_ + threadIdx.x];
  __syncthreads();
#pragma unroll
  for (int q = 0; q < 4; ++q) {
    int g = q * 256 + threadIdx.x;       // g = gate*256 + col
    const float* wr = Wih + g * E_;
    float a = 0.f;
#pragma unroll 4
    for (int k = 0; k < E_; k += 4) {
      float4 w4 = *(const float4*)(wr + k);
      float4 e4 = *(const float4*)(es + k);
      a += w4.x * e4.x + w4.y * e4.y + w4.z * e4.z + w4.w * e4.w;
    }
    int gate = g >> 8, col = g & 255;
    union { __hip_bfloat16 b; unsigned short u; } cv;
    cv.b = __float2bfloat16(a + b1[g] + b2[g]);
    ep4[((((dir * V_ + v) << 8) + col) << 2) + gate] = cv.u;
  }
}

// ---------------------------------------------------------------------------
// K1b: pack Whh^T (256 x 1024) per dir into per-WAVE-contiguous MFMA
// B-fragment layout:  Bpack[dir][ks][w][f][lane][8 elems]  (bf16)
//   f = u*2 + jj -> nt = u*16 + 2*w + jj
//   elem j: Bmat[k][n] = Whh[n][k], k = ks*32 + (lane>>4)*8 + j,
//                                   n = nt*16 + (lane&15)
// ---------------------------------------------------------------------------
__global__ __launch_bounds__(64) void k_pack(
    const float* __restrict__ Whh_f, const float* __restrict__ Whh_b,
    __hip_bfloat16* __restrict__ Bpack) {
  const int lane = threadIdx.x;
  const int f    = blockIdx.x & 7;
  const int w    = (blockIdx.x >> 3) & 7;
  const int ks   = (blockIdx.x >> 6) % KS_;
  const int dir  = blockIdx.x / (64 * KS_);
  const float* Whh = dir ? Whh_b : Whh_f;
  const int u  = f >> 1, jj = f & 1;
  const int nt = u * 16 + 2 * w + jj;
  const int n  = nt * 16 + (lane & 15);
  const int k0 = ks * 32 + (lane >> 4) * 8;
  size_t base = ((((size_t)(dir * KS_ + ks) * 8 + w) * 8 + f) * 64 + lane) * 8;
#pragma unroll
  for (int j = 0; j < 8; ++j)
    Bpack[base + j] = __float2bfloat16(Whh[n * H_ + k0 + j]);
}

// ---------------------------------------------------------------------------
// K1c: deterministic stable counting sort of words by length, DESCENDING.
// ---------------------------------------------------------------------------
#define NCHUNK 8
#define CHSZ  (NW / NCHUNK)
__global__ __launch_bounds__(256) void k_sort(const int* __restrict__ word_lens,
                                              int* __restrict__ perm) {
  __shared__ int cnt_s[NCHUNK][33];
  __shared__ int off_s[NCHUNK][33];
  const int tid = threadIdx.x;
  const int ch  = tid >> 5;
  const int ln  = (tid & 31) + 1;   // 1..32
  const int base = ch * CHSZ;
  int c = 0;
  for (int i = 0; i < CHSZ; ++i) c += (word_lens[base + i] == ln);
  cnt_s[ch][ln] = c;
  __syncthreads();
  if (tid == 0) {
    int run = 0;
    for (int l = 32; l >= 1; --l)
      for (int c2 = 0; c2 < NCHUNK; ++c2) { off_s[c2][l] = run; run += cnt_s[c2][l]; }
  }
  __syncthreads();
  int ptr = off_s[ch][ln];
  for (int i = 0; i < CHSZ; ++i) {
    int wi = base + i;
    if (word_lens[wi] == ln) perm[ptr++] = wi;
  }
}

// ---------------------------------------------------------------------------
// K2: MFMA BiLSTM recurrence. Block = 64 sorted words x 1 dir, 8 waves,
// 256 blocks total -> exactly 1 block/CU; makespan = 32 steps (longest chunk).
// Wave w owns gate-cols {2w, 2w+1}; acc[u][jj][mt] (mt=0..3) = 128 f32 (AGPR).
// Arch regs kept lean: ONE LDS addr reg (imm offsets mt*8448+ks*64) and two
// global B pointers (imm offsets 0..3072; += 65536/ks). acc initialized from
// the bf16 ep4 gather (replaces zero-init + add, overlaps gather latency).
// C/D layout (verified m89): word = mt*16 + (lane>>4)*4 + reg, col = lane&15.
// ---------------------------------------------------------------------------
__global__ __launch_bounds__(512, 1) void k_lstm(
    const int* __restrict__ char_ids, const int* __restrict__ word_lens,
    const int* __restrict__ perm, const unsigned short* __restrict__ ep4,
    const __hip_bfloat16* __restrict__ Bpack, unsigned short* __restrict__ hcat) {
  const int tid  = threadIdx.x;
  const int lane = tid & 63;
  const int w    = tid >> 6;       // wave 0..7
  const int bid  = blockIdx.x;
  const int dir  = bid & 1;
  const int w0   = (bid >> 1) * M_;

  __shared__ unsigned short hL[M_][KPAD];  // 33.8 KB
  __shared__ int ids_s[M_][L_ + 1];        // 8.4 KB (pad -> bank spread)
  __shared__ int len_s[M_];
  __shared__ int pw_s[M_];

  if (tid < M_) {
    int gw = perm[w0 + tid];
    pw_s[tid]  = gw;
    len_s[tid] = word_lens[gw];
  }
  __syncthreads();
  for (int i = tid; i < M_ * L_; i += 512) {
    int q = i >> 5;
    ids_s[q][i & 31] = char_ids[pw_s[q] * L_ + (i & 31)];
  }
  for (int i = tid; i < M_ * KPAD / 2; i += 512) ((unsigned int*)hL)[i] = 0u;
  __syncthreads();

  int mlen = 0;
#pragma unroll 8
  for (int m = 0; m < M_; ++m) mlen = max(mlen, len_s[m]);
  unsigned lrp[4];
#pragma unroll
  for (int mt = 0; mt < 4; ++mt) {
    int bw = mt * 16 + ((lane >> 4) << 2);
    lrp[mt] = (unsigned)len_s[bw] | ((unsigned)len_s[bw + 1] << 8) |
              ((unsigned)len_s[bw + 2] << 16) | ((unsigned)len_s[bw + 3] << 24);
  }

  // per-dir, per-wave base: Bpack[dir][ks=0][w][0][lane][0]; ks stride 65536
  const char* Bb0 = (const char*)Bpack + (size_t)dir * (KS_ * 8 * 8 * 64 * 16)
                    + (size_t)w * (8 * 64 * 16) + (size_t)lane * 16;
  // single LDS addr: A-frag (mt,ks) at ar + mt*8448 + ks*64
  const char* ar = (const char*)&hL[lane & 15][0] + ((lane >> 4) << 4);
  const ushort4* epv = (const ushort4*)ep4 + ((size_t)dir << 15);  // dir*V*256
  const int p0 = 2 * w * 16 + (lane & 15);   // col of jj=0 (jj=1: +16)
  const int g4 = (lane >> 4) << 2;

  float c_[2][4][4];                         // [jj][mt][r]
#pragma unroll
  for (int jj = 0; jj < 2; ++jj)
#pragma unroll
    for (int mt = 0; mt < 4; ++mt)
#pragma unroll
      for (int r = 0; r < 4; ++r) c_[jj][mt][r] = 0.f;

  for (int t = 0; t < mlen; ++t) {
    // acc init from ep4 gather (bf16 ushort4: 4 gates per load)
    f4v acc[4][2][4];                        // [gate u][jj][mt]
#pragma unroll
    for (int mt = 0; mt < 4; ++mt) {
#pragma unroll
      for (int r = 0; r < 4; ++r) {
        int len = (int)((lrp[mt] >> (8 * r)) & 255u);
        int tt  = dir ? max(len - 1 - t, 0) : t;
        int id  = ids_s[mt * 16 + g4 + r][tt];
        ushort4 x0 = epv[(id << 8) + p0];
        ushort4 x1 = epv[(id << 8) + p0 + 16];
        acc[0][0][mt][r] = b2f(x0.x); acc[1][0][mt][r] = b2f(x0.y);
        acc[2][0][mt][r] = b2f(x0.z); acc[3][0][mt][r] = b2f(x0.w);
        acc[0][1][mt][r] = b2f(x1.x); acc[1][1][mt][r] = b2f(x1.y);
        acc[2][1][mt][r] = b2f(x1.z); acc[3][1][mt][r] = b2f(x1.w);
      }
    }

    const char* bp0 = Bb0;            // fragments 0..3 (imm offs 0..3072)
    const char* bp1 = Bb0 + 4096;     // fragments 4..7
#pragma unroll
    for (int ks = 0; ks < KS_; ++ks) {
      s8v af0 = *(const s8v*)(ar + 0     + ks * 64);
      s8v af1 = *(const s8v*)(ar + 8448  + ks * 64);
      s8v af2 = *(const s8v*)(ar + 16896 + ks * 64);
      s8v af3 = *(const s8v*)(ar + 25344 + ks * 64);
      s8v b0 = *(const s8v*)(bp0 + 0);
      s8v b1 = *(const s8v*)(bp0 + 1024);
      s8v b2 = *(const s8v*)(bp0 + 2048);
      s8v b3 = *(const s8v*)(bp0 + 3072);
      s8v b4 = *(const s8v*)(bp1 + 0);
      s8v b5 = *(const s8v*)(bp1 + 1024);
      s8v b6 = *(const s8v*)(bp1 + 2048);
      s8v b7 = *(const s8v*)(bp1 + 3072);
      acc[0][0][0] = __builtin_amdgcn_mfma_f32_16x16x32_bf16(af0, b0, acc[0][0][0], 0, 0, 0);
      acc[0][0][1] = __builtin_amdgcn_mfma_f32_16x16x32_bf16(af1, b0, acc[0][0][1], 0, 0, 0);
      acc[0][0][2] = __builtin_amdgcn_mfma_f32_16x16x32_bf16(af2, b0, acc[0][0][2], 0, 0, 0);
      acc[0][0][3] = __builtin_amdgcn_mfma_f32_16x16x32_bf16(af3, b0, acc[0][0][3], 0, 0, 0);
      acc[0][1][0] = __builtin_amdgcn_mfma_f32_16x16x32_bf16(af0, b1, acc[0][1][0], 0, 0, 0);
      acc[0][1][1] = __builtin_amdgcn_mfma_f32_16x16x32_bf16(af1, b1, acc[0][1][1], 0, 0, 0);
      acc[0][1][2] = __builtin_amdgcn_mfma_f32_16x16x32_bf16(af2, b1, acc[0][1][2], 0, 0, 0);
      acc[0][1][3] = __builtin_amdgcn_mfma_f32_16x16x32_bf16(af3, b1, acc[0][1][3], 0, 0, 0);
      acc[1][0][0] = __builtin_amdgcn_mfma_f32_16x16x32_bf16(af0, b2, acc[1][0][0], 0, 0, 0);
      acc[1][0][1] = __builtin_amdgcn_mfma_f32_16x16x32_bf16(af1, b2, acc[1][0][1], 0, 0, 0);
      acc[1][0][2] = __builtin_amdgcn_mfma_f32_16x16x32_bf16(af2, b2, acc[1][0][2], 0, 0, 0);
      acc[1][0][3] = __builtin_amdgcn_mfma_f32_16x16x32_bf16(af3, b2, acc[1][0][3], 0, 0, 0);
      acc[1][1][0] = __builtin_amdgcn_mfma_f32_16x16x32_bf16(af0, b3, acc[1][1][0], 0, 0, 0);
      acc[1][1][1] = __builtin_amdgcn_mfma_f32_16x16x32_bf16(af1, b3, acc[1][1][1], 0, 0, 0);
      acc[1][1][2] = __builtin_amdgcn_mfma_f32_16x16x32_bf16(af2, b3, acc[1][1][2], 0, 0, 0);
      acc[1][1][3] = __builtin_amdgcn_mfma_f32_16x16x32_bf16(af3, b3, acc[1][1][3], 0, 0, 0);
      acc[2][0][0] = __builtin_amdgcn_mfma_f32_16x16x32_bf16(af0, b4, acc[2][0][0], 0, 0, 0);
      acc[2][0][1] = __builtin_amdgcn_mfma_f32_16x16x32_bf16(af1, b4, acc[2][0][1], 0, 0, 0);
      acc[2][0][2] = __builtin_amdgcn_mfma_f32_16x16x32_bf16(af2, b4, acc[2][0][2], 0, 0, 0);
      acc[2][0][3] = __builtin_amdgcn_mfma_f32_16x16x32_bf16(af3, b4, acc[2][0][3], 0, 0, 0);
      acc[2][1][0] = __builtin_amdgcn_mfma_f32_16x16x32_bf16(af0, b5, acc[2][1][0], 0, 0, 0);
      acc[2][1][1] = __builtin_amdgcn_mfma_f32_16x16x32_bf16(af1, b5, acc[2][1][1], 0, 0, 0);
      acc[2][1][2] = __builtin_amdgcn_mfma_f32_16x16x32_bf16(af2, b5, acc[2][1][2], 0, 0, 0);
      acc[2][1][3] = __builtin_amdgcn_mfma_f32_16x16x32_bf16(af3, b5, acc[2][1][3], 0, 0, 0);
      acc[3][0][0] = __builtin_amdgcn_mfma_f32_16x16x32_bf16(af0, b6, acc[3][0][0], 0, 0, 0);
      acc[3][0][1] = __builtin_amdgcn_mfma_f32_16x16x32_bf16(af1, b6, acc[3][0][1], 0, 0, 0);
      acc[3][0][2] = __builtin_amdgcn_mfma_f32_16x16x32_bf16(af2, b6, acc[3][0][2], 0, 0, 0);
      acc[3][0][3] = __builtin_amdgcn_mfma_f32_16x16x32_bf16(af3, b6, acc[3][0][3], 0, 0, 0);
      acc[3][1][0] = __builtin_amdgcn_mfma_f32_16x16x32_bf16(af0, b7, acc[3][1][0], 0, 0, 0);
      acc[3][1][1] = __builtin_amdgcn_mfma_f32_16x16x32_bf16(af1, b7, acc[3][1][1], 0, 0, 0);
      acc[3][1][2] = __builtin_amdgcn_mfma_f32_16x16x32_bf16(af2, b7, acc[3][1][2], 0, 0, 0);
      acc[3][1][3] = __builtin_amdgcn_mfma_f32_16x16x32_bf16(af3, b7, acc[3][1][3], 0, 0, 0);
      bp0 += 65536;
      bp1 += 65536;
    }

    __syncthreads();   // all waves done reading hL for step t

    // elementwise gates + masked state update; write h_new (bf16) to LDS
#pragma unroll
    for (int jj = 0; jj < 2; ++jj) {
#pragma unroll
      for (int mt = 0; mt < 4; ++mt) {
#pragma unroll
        for (int r = 0; r < 4; ++r) {
          const int m = mt * 16 + g4 + r;
          const int p = (2 * w + jj) * 16 + (lane & 15);
          float gi = acc[0][jj][mt][r];
          float gf = acc[1][jj][mt][r];
          float gg = acc[2][jj][mt][r];
          float go = acc[3][jj][mt][r];
          float si = 1.f / (1.f + __expf(-gi));
          float sf = 1.f / (1.f + __expf(-gf));
          float so = 1.f / (1.f + __expf(-go));
          float tg = 2.f / (1.f + __expf(-2.f * gg)) - 1.f;
          float cn = sf * c_[jj][mt][r] + si * tg;
          float hn = so * (2.f / (1.f + __expf(-2.f * cn)) - 1.f);
          int len = (int)((lrp[mt] >> (8 * r)) & 255u);
          if (t < len) {
            c_[jj][mt][r] = cn;
            union { __hip_bfloat16 b; unsigned short u; } cv;
            cv.b = __float2bfloat16(hn);
            hL[m][p] = cv.u;
          }
        }
      }
    }
    __syncthreads();   // h(t+1) visible before next MFMA phase
  }

  // write frozen h (bf16) to hcat at ORIGINAL word position: [h_bwd | h_fwd]
  const int off = dir ? 0 : H_;
  for (int i = tid; i < M_ * H_ / 8; i += 512) {   // 2048 vec8 chunks, 4 iters
    int q    = i >> 5;              // local word
    int pos  = (i & 31) << 3;       // col (multiple of 8)
    s8v v = *(const s8v*)&hL[q][pos];
    *(s8v*)&hcat[(size_t)pw_s[q] * (2 * H_) + off + pos] = v;
  }
}

// ---------------------------------------------------------------------------
// K3: wemb = hcat(bf16) @ pW^T + pb;  also writes lens_out (= W) slots.
// ---------------------------------------------------------------------------
#define PM_ 16
__global__ __launch_bounds__(256) void k_proj(
    const unsigned short* __restrict__ hcat, const float* __restrict__ pW,
    const float* __restrict__ pb, float* __restrict__ out) {
  const int tid = threadIdx.x;
  const int n0  = blockIdx.x * PM_;
  __shared__ float hs[PM_][2 * H_];   // 32 KB
  for (int i = tid; i < PM_ * 2 * H_; i += 256) {
    unsigned int ui = ((unsigned int)hcat[(size_t)n0 * 2 * H_ + i]) << 16;
    ((float*)hs)[i] = __uint_as_float(ui);
  }
  __syncthreads();

  const float* pwr = pW + tid * (2 * H_);
  float acc[PM_];
#pragma unroll
  for (int m = 0; m < PM_; ++m) acc[m] = 0.f;

#pragma unroll 2
  for (int k = 0; k < 2 * H_; k += 4) {
    float4 w4 = *(const float4*)(pwr + k);
#pragma unroll
    for (int m = 0; m < PM_; ++m) {
      float4 h4 = *(const float4*)(&hs[m][k]);
      acc[m] += w4.x * h4.x + w4.y * h4.y + w4.z * h4.z + w4.w * h4.w;
    }
  }
  const float bias = pb[tid];
#pragma unroll
  for (int m = 0; m < PM_; ++m) out[(n0 + m) * H_ + tid] = acc[m] + bias;

  if (blockIdx.x == 0 && tid < B_) out[NW * H_ + tid] = (float)W_;
}

// ---------------------------------------------------------------------------
extern "C" void kernel_launch(void* const* d_in, const int* in_sizes, int n_in,
                              void* d_out, int out_size, void* d_ws, size_t ws_size,
                              hipStream_t stream) {
  const int*   char_ids  = (const int*)  d_in[0];
  const int*   word_lens = (const int*)  d_in[1];
  const float* emb       = (const float*)d_in[2];
  const float* Wih_f     = (const float*)d_in[3];
  const float* Whh_f     = (const float*)d_in[4];
  const float* bih_f     = (const float*)d_in[5];
  const float* bhh_f     = (const float*)d_in[6];
  const float* Wih_b     = (const float*)d_in[7];
  const float* Whh_b     = (const float*)d_in[8];
  const float* bih_b     = (const float*)d_in[9];
  const float* bhh_b     = (const float*)d_in[10];
  const float* pW        = (const float*)d_in[11];
  const float* pb        = (const float*)d_in[12];
  float* out = (float*)d_out;

  // ws layout: [Bpack 1MB][ep4(bf16) 512KB][perm 32KB][hcat(bf16) 8.4MB]
  const size_t BPACK_BYTES = (size_t)2 * KS_ * 8 * 8 * 64 * 8 * 2;   // 1 MB
  const size_t EP4_BYTES   = (size_t)2 * V_ * 256 * 4 * 2;           // 512 KB
  __hip_bfloat16* Bpack = (__hip_bfloat16*)d_ws;
  unsigned short* ep4 = (unsigned short*)((char*)d_ws + BPACK_BYTES);
  int* perm = (int*)((char*)d_ws + BPACK_BYTES + EP4_BYTES);
  unsigned short* hcat = (unsigned short*)((char*)d_ws + BPACK_BYTES + EP4_BYTES + NW * sizeof(int));

  k_sort<<<dim3(1), dim3(256), 0, stream>>>(word_lens, perm);
  k_embproj<<<dim3(2 * V_), dim3(256), 0, stream>>>(emb, Wih_f, bih_f, bhh_f,
                                                    Wih_b, bih_b, bhh_b, ep4);
  k_pack<<<dim3(2 * KS_ * 64), dim3(64), 0, stream>>>(Whh_f, Whh_b, Bpack);
  k_lstm<<<dim3(2 * NW / M_), dim3(512), 0, stream>>>(char_ids, word_lens, perm, ep4, Bpack, hcat);
  k_proj<<<dim3(NW / PM_), dim3(256), 0, stream>>>(hcat, pW, pb, out);
}

// Round 10
// 1046.490 us; speedup vs baseline: 1.3678x; 1.3678x over previous
//
#include <hip/hip_runtime.h>
#include <hip/hip_bf16.h>
#include <math.h>

// Problem constants
#define B_  64
#define W_  128
#define L_  32
#define V_  128
#define E_  128
#define H_  256
#define G4_ 1024      // 4*H
#define NW  8192      // B*W words
#define KS_ 8         // MFMA k-steps: h only (K=256)
#define KPAD 264      // padded LDS row (bf16): 256 used + 8 pad (528B = 33*16B, odd)
#define M_  32        // words per block

typedef short s8v  __attribute__((ext_vector_type(8)));  // 8 bf16 (4 VGPR)
typedef float f4v  __attribute__((ext_vector_type(4)));

static __device__ __forceinline__ float b2f(unsigned short u) {
  return __uint_as_float(((unsigned int)u) << 16);
}

// ---------------------------------------------------------------------------
// K1: ep4[dir][v][col][gate] = bf16( dot(emb[v], Wih_dir[gate*256+col]) + biases )
// gate-last ushort4: one 8B load gives all 4 gate pre-activations.
// ---------------------------------------------------------------------------
__global__ __launch_bounds__(256) void k_embproj(
    const float* __restrict__ emb,
    const float* __restrict__ Wih_f, const float* __restrict__ bih_f, const float* __restrict__ bhh_f,
    const float* __restrict__ Wih_b, const float* __restrict__ bih_b, const float* __restrict__ bhh_b,
    unsigned short* __restrict__ ep4) {
  int v   = blockIdx.x & (V_ - 1);
  int dir = blockIdx.x >> 7;
  const float* Wih = dir ? Wih_b : Wih_f;
  const float* b1  = dir ? bih_b : bih_f;
  const float* b2  = dir ? bhh_b : bhh_f;
  __shared__ float es[E_];
  if (threadIdx.x < E_) es[threadIdx.x] = emb[v * E_ + threadIdx.x];
  __syncthreads();
#pragma unroll
  for (int q = 0; q < 4; ++q) {
    int g = q * 256 + threadIdx.x;       // g = gate*256 + col
    const float* wr = Wih + g * E_;
    float a = 0.f;
#pragma unroll 4
    for (int k = 0; k < E_; k += 4) {
      float4 w4 = *(const float4*)(wr + k);
      float4 e4 = *(const float4*)(es + k);
      a += w4.x * e4.x + w4.y * e4.y + w4.z * e4.z + w4.w * e4.w;
    }
    int gate = g >> 8, col = g & 255;
    union { __hip_bfloat16 b; unsigned short u; } cv;
    cv.b = __float2bfloat16(a + b1[g] + b2[g]);
    ep4[((((dir * V_ + v) << 8) + col) << 2) + gate] = cv.u;
  }
}

// ---------------------------------------------------------------------------
// K1b: pack Whh^T (256 x 1024) per dir into per-WAVE-contiguous MFMA
// B-fragment layout:  Bpack[dir][ks][w][f][lane][8 elems]  (bf16)
//   f = u*2 + jj -> nt = u*16 + 2*w + jj
//   elem j: Bmat[k][n] = Whh[n][k], k = ks*32 + (lane>>4)*8 + j,
//                                   n = nt*16 + (lane&15)
// ---------------------------------------------------------------------------
__global__ __launch_bounds__(64) void k_pack(
    const float* __restrict__ Whh_f, const float* __restrict__ Whh_b,
    __hip_bfloat16* __restrict__ Bpack) {
  const int lane = threadIdx.x;
  const int f    = blockIdx.x & 7;
  const int w    = (blockIdx.x >> 3) & 7;
  const int ks   = (blockIdx.x >> 6) % KS_;
  const int dir  = blockIdx.x / (64 * KS_);
  const float* Whh = dir ? Whh_b : Whh_f;
  const int u  = f >> 1, jj = f & 1;
  const int nt = u * 16 + 2 * w + jj;
  const int n  = nt * 16 + (lane & 15);
  const int k0 = ks * 32 + (lane >> 4) * 8;
  size_t base = ((((size_t)(dir * KS_ + ks) * 8 + w) * 8 + f) * 64 + lane) * 8;
#pragma unroll
  for (int j = 0; j < 8; ++j)
    Bpack[base + j] = __float2bfloat16(Whh[n * H_ + k0 + j]);
}

// ---------------------------------------------------------------------------
// K1c: deterministic stable counting sort of words by length, DESCENDING.
// ---------------------------------------------------------------------------
#define NCHUNK 8
#define CHSZ  (NW / NCHUNK)
__global__ __launch_bounds__(256) void k_sort(const int* __restrict__ word_lens,
                                              int* __restrict__ perm) {
  __shared__ int cnt_s[NCHUNK][33];
  __shared__ int off_s[NCHUNK][33];
  const int tid = threadIdx.x;
  const int ch  = tid >> 5;
  const int ln  = (tid & 31) + 1;   // 1..32
  const int base = ch * CHSZ;
  int c = 0;
  for (int i = 0; i < CHSZ; ++i) c += (word_lens[base + i] == ln);
  cnt_s[ch][ln] = c;
  __syncthreads();
  if (tid == 0) {
    int run = 0;
    for (int l = 32; l >= 1; --l)
      for (int c2 = 0; c2 < NCHUNK; ++c2) { off_s[c2][l] = run; run += cnt_s[c2][l]; }
  }
  __syncthreads();
  int ptr = off_s[ch][ln];
  for (int i = 0; i < CHSZ; ++i) {
    int wi = base + i;
    if (word_lens[wi] == ln) perm[ptr++] = wi;
  }
}

// ---------------------------------------------------------------------------
// K2: MFMA BiLSTM recurrence. Block = 32 sorted words x 1 dir, 8 waves.
// LPT pairing: bid<256 -> task bid, else 767-bid (CU c gets long+short).
// Per step: [issue 16 ep4 gather loads] -> [B-stream + 128 MFMA, C=0 at ks0,
// reads hL buf[t&1]] -> [elementwise: +xw, gates, h in REGS, unconditional
// ds_write to buf[(t+1)&1]] -> ONE barrier.  Double-buffered hL means MFMA
// reads and h writes never touch the same buffer between barriers.
// C/D layout (verified m89): word = mt*16 + (lane>>4)*4 + reg, col = lane&15.
// ---------------------------------------------------------------------------
__global__ __launch_bounds__(512, 2) void k_lstm(
    const int* __restrict__ char_ids, const int* __restrict__ word_lens,
    const int* __restrict__ perm, const unsigned short* __restrict__ ep4,
    const __hip_bfloat16* __restrict__ Bpack, unsigned short* __restrict__ hcat) {
  const int tid  = threadIdx.x;
  const int lane = tid & 63;
  const int w    = tid >> 6;       // wave 0..7
  const int bid  = blockIdx.x;
  const int s    = (bid < 256) ? bid : 767 - bid;
  const int dir  = s & 1;
  const int w0   = (s >> 1) * M_;

  __shared__ unsigned short hL[2][M_][KPAD];  // 33.8 KB (double buffer)
  __shared__ int ids_s[M_][L_ + 1];           // 4.2 KB
  __shared__ int len_s[M_];
  __shared__ int pw_s[M_];

  if (tid < M_) {
    int gw = perm[w0 + tid];
    pw_s[tid]  = gw;
    len_s[tid] = word_lens[gw];
  }
  __syncthreads();
  for (int i = tid; i < M_ * L_; i += 512) {
    int q = i >> 5;
    ids_s[q][i & 31] = char_ids[pw_s[q] * L_ + (i & 31)];
  }
  // zero buf0 (h(0)=0); buf1 is fully written by elementwise(0)
  for (int i = tid; i < M_ * KPAD / 2; i += 512) ((unsigned int*)hL[0])[i] = 0u;
  __syncthreads();

  int mlen = 0;
#pragma unroll 8
  for (int m = 0; m < M_; ++m) mlen = max(mlen, len_s[m]);
  unsigned lrp[2];
#pragma unroll
  for (int mt = 0; mt < 2; ++mt) {
    int bw = mt * 16 + ((lane >> 4) << 2);
    lrp[mt] = (unsigned)len_s[bw] | ((unsigned)len_s[bw + 1] << 8) |
              ((unsigned)len_s[bw + 2] << 16) | ((unsigned)len_s[bw + 3] << 24);
  }

  // per-dir, per-wave B base: Bpack[dir][ks=0][w][0][lane][0]; ks stride 64KB
  const char* Bb0 = (const char*)Bpack + (size_t)dir * (KS_ * 8 * 8 * 64 * 16)
                    + (size_t)w * (8 * 64 * 16) + (size_t)lane * 16;
  // A-frag read bases (per buffer): + mt*8448 + ks*64 (imm offsets)
  const char* arA = (const char*)&hL[0][lane & 15][0] + ((lane >> 4) << 4);
  const char* arB = arA + M_ * KPAD * 2;
  // h-write base (per buffer): + mt*8448 + r*528 + jj*32 (imm offsets)
  unsigned short* hwA = &hL[0][(lane >> 4) << 2][2 * w * 16 + (lane & 15)];
  unsigned short* hwB = hwA + M_ * KPAD;
  const ushort4* epv = (const ushort4*)ep4 + ((size_t)dir << 15);  // dir*V*256
  const int p0 = 2 * w * 16 + (lane & 15);   // gather col of jj=0 (jj=1: +16)
  const int g4 = (lane >> 4) << 2;

  float c_[2][2][4];                         // [jj][mt][r]
  unsigned short hr[2][2][4];                // bf16 h of owned elems
#pragma unroll
  for (int jj = 0; jj < 2; ++jj)
#pragma unroll
    for (int mt = 0; mt < 2; ++mt)
#pragma unroll
      for (int r = 0; r < 4; ++r) { c_[jj][mt][r] = 0.f; hr[jj][mt][r] = 0; }

  for (int t = 0; t < mlen; ++t) {
    // --- issue ep4 gathers for THIS step first; consumed after MFMA phase ---
    ushort4 xc0[2][4], xc1[2][4];            // [mt][r]
#pragma unroll
    for (int mt = 0; mt < 2; ++mt) {
#pragma unroll
      for (int r = 0; r < 4; ++r) {
        int len = (int)((lrp[mt] >> (8 * r)) & 255u);
        int tt  = dir ? max(len - 1 - t, 0) : t;   // t < mlen <= 32 in-bounds
        int id  = ids_s[mt * 16 + g4 + r][tt];
        xc0[mt][r] = epv[(id << 8) + p0];
        xc1[mt][r] = epv[(id << 8) + p0 + 16];
      }
    }

    // --- MFMA phase: reads hL buf[t&1]; acc zero-init via C=0 at ks=0 ---
    const char* ar = (t & 1) ? arB : arA;
    f4v acc[4][2][2];                        // [gate u][jj][mt]
    const char* bp0 = Bb0;                   // frags 0..3 (imm 0..3072)
    const char* bp1 = Bb0 + 4096;            // frags 4..7
    {
      const f4v Z = (f4v){0.f, 0.f, 0.f, 0.f};
      s8v af0 = *(const s8v*)(ar + 0);
      s8v af1 = *(const s8v*)(ar + 8448);
      s8v b0 = *(const s8v*)(bp0 + 0);
      s8v b1 = *(const s8v*)(bp0 + 1024);
      s8v b2 = *(const s8v*)(bp0 + 2048);
      s8v b3 = *(const s8v*)(bp0 + 3072);
      s8v b4 = *(const s8v*)(bp1 + 0);
      s8v b5 = *(const s8v*)(bp1 + 1024);
      s8v b6 = *(const s8v*)(bp1 + 2048);
      s8v b7 = *(const s8v*)(bp1 + 3072);
      acc[0][0][0] = __builtin_amdgcn_mfma_f32_16x16x32_bf16(af0, b0, Z, 0, 0, 0);
      acc[0][0][1] = __builtin_amdgcn_mfma_f32_16x16x32_bf16(af1, b0, Z, 0, 0, 0);
      acc[0][1][0] = __builtin_amdgcn_mfma_f32_16x16x32_bf16(af0, b1, Z, 0, 0, 0);
      acc[0][1][1] = __builtin_amdgcn_mfma_f32_16x16x32_bf16(af1, b1, Z, 0, 0, 0);
      acc[1][0][0] = __builtin_amdgcn_mfma_f32_16x16x32_bf16(af0, b2, Z, 0, 0, 0);
      acc[1][0][1] = __builtin_amdgcn_mfma_f32_16x16x32_bf16(af1, b2, Z, 0, 0, 0);
      acc[1][1][0] = __builtin_amdgcn_mfma_f32_16x16x32_bf16(af0, b3, Z, 0, 0, 0);
      acc[1][1][1] = __builtin_amdgcn_mfma_f32_16x16x32_bf16(af1, b3, Z, 0, 0, 0);
      acc[2][0][0] = __builtin_amdgcn_mfma_f32_16x16x32_bf16(af0, b4, Z, 0, 0, 0);
      acc[2][0][1] = __builtin_amdgcn_mfma_f32_16x16x32_bf16(af1, b4, Z, 0, 0, 0);
      acc[2][1][0] = __builtin_amdgcn_mfma_f32_16x16x32_bf16(af0, b5, Z, 0, 0, 0);
      acc[2][1][1] = __builtin_amdgcn_mfma_f32_16x16x32_bf16(af1, b5, Z, 0, 0, 0);
      acc[3][0][0] = __builtin_amdgcn_mfma_f32_16x16x32_bf16(af0, b6, Z, 0, 0, 0);
      acc[3][0][1] = __builtin_amdgcn_mfma_f32_16x16x32_bf16(af1, b6, Z, 0, 0, 0);
      acc[3][1][0] = __builtin_amdgcn_mfma_f32_16x16x32_bf16(af0, b7, Z, 0, 0, 0);
      acc[3][1][1] = __builtin_amdgcn_mfma_f32_16x16x32_bf16(af1, b7, Z, 0, 0, 0);
      bp0 += 65536;
      bp1 += 65536;
    }
#pragma unroll
    for (int ks = 1; ks < KS_; ++ks) {
      s8v af0 = *(const s8v*)(ar + ks * 64);
      s8v af1 = *(const s8v*)(ar + 8448 + ks * 64);
      s8v b0 = *(const s8v*)(bp0 + 0);
      s8v b1 = *(const s8v*)(bp0 + 1024);
      s8v b2 = *(const s8v*)(bp0 + 2048);
      s8v b3 = *(const s8v*)(bp0 + 3072);
      s8v b4 = *(const s8v*)(bp1 + 0);
      s8v b5 = *(const s8v*)(bp1 + 1024);
      s8v b6 = *(const s8v*)(bp1 + 2048);
      s8v b7 = *(const s8v*)(bp1 + 3072);
      acc[0][0][0] = __builtin_amdgcn_mfma_f32_16x16x32_bf16(af0, b0, acc[0][0][0], 0, 0, 0);
      acc[0][0][1] = __builtin_amdgcn_mfma_f32_16x16x32_bf16(af1, b0, acc[0][0][1], 0, 0, 0);
      acc[0][1][0] = __builtin_amdgcn_mfma_f32_16x16x32_bf16(af0, b1, acc[0][1][0], 0, 0, 0);
      acc[0][1][1] = __builtin_amdgcn_mfma_f32_16x16x32_bf16(af1, b1, acc[0][1][1], 0, 0, 0);
      acc[1][0][0] = __builtin_amdgcn_mfma_f32_16x16x32_bf16(af0, b2, acc[1][0][0], 0, 0, 0);
      acc[1][0][1] = __builtin_amdgcn_mfma_f32_16x16x32_bf16(af1, b2, acc[1][0][1], 0, 0, 0);
      acc[1][1][0] = __builtin_amdgcn_mfma_f32_16x16x32_bf16(af0, b3, acc[1][1][0], 0, 0, 0);
      acc[1][1][1] = __builtin_amdgcn_mfma_f32_16x16x32_bf16(af1, b3, acc[1][1][1], 0, 0, 0);
      acc[2][0][0] = __builtin_amdgcn_mfma_f32_16x16x32_bf16(af0, b4, acc[2][0][0], 0, 0, 0);
      acc[2][0][1] = __builtin_amdgcn_mfma_f32_16x16x32_bf16(af1, b4, acc[2][0][1], 0, 0, 0);
      acc[2][1][0] = __builtin_amdgcn_mfma_f32_16x16x32_bf16(af0, b5, acc[2][1][0], 0, 0, 0);
      acc[2][1][1] = __builtin_amdgcn_mfma_f32_16x16x32_bf16(af1, b5, acc[2][1][1], 0, 0, 0);
      acc[3][0][0] = __builtin_amdgcn_mfma_f32_16x16x32_bf16(af0, b6, acc[3][0][0], 0, 0, 0);
      acc[3][0][1] = __builtin_amdgcn_mfma_f32_16x16x32_bf16(af1, b6, acc[3][0][1], 0, 0, 0);
      acc[3][1][0] = __builtin_amdgcn_mfma_f32_16x16x32_bf16(af0, b7, acc[3][1][0], 0, 0, 0);
      acc[3][1][1] = __builtin_amdgcn_mfma_f32_16x16x32_bf16(af1, b7, acc[3][1][1], 0, 0, 0);
      bp0 += 65536;
      bp1 += 65536;
    }

    // --- elementwise: +xw, gates, select-update h/c, write buf[(t+1)&1] ---
    unsigned short* hw = (t & 1) ? hwA : hwB;   // (t+1)&1 buffer
#pragma unroll
    for (int jj = 0; jj < 2; ++jj) {
#pragma unroll
      for (int mt = 0; mt < 2; ++mt) {
#pragma unroll
        for (int r = 0; r < 4; ++r) {
          ushort4 xw = jj ? xc1[mt][r] : xc0[mt][r];
          float gi = acc[0][jj][mt][r] + b2f(xw.x);
          float gf = acc[1][jj][mt][r] + b2f(xw.y);
          float gg = acc[2][jj][mt][r] + b2f(xw.z);
          float go = acc[3][jj][mt][r] + b2f(xw.w);
          float si = 1.f / (1.f + __expf(-gi));
          float sf = 1.f / (1.f + __expf(-gf));
          float so = 1.f / (1.f + __expf(-go));
          float tg = 2.f / (1.f + __expf(-2.f * gg)) - 1.f;
          float cn = sf * c_[jj][mt][r] + si * tg;
          float hn = so * (2.f / (1.f + __expf(-2.f * cn)) - 1.f);
          int  len = (int)((lrp[mt] >> (8 * r)) & 255u);
          bool act = t < len;
          c_[jj][mt][r] = act ? cn : c_[jj][mt][r];
          union { __hip_bfloat16 b; unsigned short u; } cv;
          cv.b = __float2bfloat16(hn);
          hr[jj][mt][r] = act ? cv.u : hr[jj][mt][r];
          hw[mt * 16 * KPAD + r * KPAD + jj * 16] = hr[jj][mt][r];
        }
      }
    }
    __syncthreads();   // writes to buf[(t+1)&1] visible; next MFMA may proceed
  }

  // write frozen h (from regs) to hcat at ORIGINAL word pos: [h_bwd | h_fwd]
  const int off = dir ? 0 : H_;
#pragma unroll
  for (int jj = 0; jj < 2; ++jj) {
#pragma unroll
    for (int mt = 0; mt < 2; ++mt) {
#pragma unroll
      for (int r = 0; r < 4; ++r) {
        int m = mt * 16 + g4 + r;
        int p = (2 * w + jj) * 16 + (lane & 15);
        hcat[(size_t)pw_s[m] * (2 * H_) + off + p] = hr[jj][mt][r];
      }
    }
  }
}

// ---------------------------------------------------------------------------
// K3: wemb = hcat(bf16) @ pW^T + pb;  also writes lens_out (= W) slots.
// ---------------------------------------------------------------------------
#define PM_ 16
__global__ __launch_bounds__(256) void k_proj(
    const unsigned short* __restrict__ hcat, const float* __restrict__ pW,
    const float* __restrict__ pb, float* __restrict__ out) {
  const int tid = threadIdx.x;
  const int n0  = blockIdx.x * PM_;
  __shared__ float hs[PM_][2 * H_];   // 32 KB
  for (int i = tid; i < PM_ * 2 * H_; i += 256) {
    unsigned int ui = ((unsigned int)hcat[(size_t)n0 * 2 * H_ + i]) << 16;
    ((float*)hs)[i] = __uint_as_float(ui);
  }
  __syncthreads();

  const float* pwr = pW + tid * (2 * H_);
  float acc[PM_];
#pragma unroll
  for (int m = 0; m < PM_; ++m) acc[m] = 0.f;

#pragma unroll 2
  for (int k = 0; k < 2 * H_; k += 4) {
    float4 w4 = *(const float4*)(pwr + k);
#pragma unroll
    for (int m = 0; m < PM_; ++m) {
      float4 h4 = *(const float4*)(&hs[m][k]);
      acc[m] += w4.x * h4.x + w4.y * h4.y + w4.z * h4.z + w4.w * h4.w;
    }
  }
  const float bias = pb[tid];
#pragma unroll
  for (int m = 0; m < PM_; ++m) out[(n0 + m) * H_ + tid] = acc[m] + bias;

  if (blockIdx.x == 0 && tid < B_) out[NW * H_ + tid] = (float)W_;
}

// ---------------------------------------------------------------------------
extern "C" void kernel_launch(void* const* d_in, const int* in_sizes, int n_in,
                              void* d_out, int out_size, void* d_ws, size_t ws_size,
                              hipStream_t stream) {
  const int*   char_ids  = (const int*)  d_in[0];
  const int*   word_lens = (const int*)  d_in[1];
  const float* emb       = (const float*)d_in[2];
  const float* Wih_f     = (const float*)d_in[3];
  const float* Whh_f     = (const float*)d_in[4];
  const float* bih_f     = (const float*)d_in[5];
  const float* bhh_f     = (const float*)d_in[6];
  const float* Wih_b     = (const float*)d_in[7];
  const float* Whh_b     = (const float*)d_in[8];
  const float* bih_b     = (const float*)d_in[9];
  const float* bhh_b     = (const float*)d_in[10];
  const float* pW        = (const float*)d_in[11];
  const float* pb        = (const float*)d_in[12];
  float* out = (float*)d_out;

  // ws layout: [Bpack 1MB][ep4(bf16) 512KB][perm 32KB][hcat(bf16) 8.4MB]
  const size_t BPACK_BYTES = (size_t)2 * KS_ * 8 * 8 * 64 * 8 * 2;   // 1 MB
  const size_t EP4_BYTES   = (size_t)2 * V_ * 256 * 4 * 2;           // 512 KB
  __hip_bfloat16* Bpack = (__hip_bfloat16*)d_ws;
  unsigned short* ep4 = (unsigned short*)((char*)d_ws + BPACK_BYTES);
  int* perm = (int*)((char*)d_ws + BPACK_BYTES + EP4_BYTES);
  unsigned short* hcat = (unsigned short*)((char*)d_ws + BPACK_BYTES + EP4_BYTES + NW * sizeof(int));

  k_sort<<<dim3(1), dim3(256), 0, stream>>>(word_lens, perm);
  k_embproj<<<dim3(2 * V_), dim3(256), 0, stream>>>(emb, Wih_f, bih_f, bhh_f,
                                                    Wih_b, bih_b, bhh_b, ep4);
  k_pack<<<dim3(2 * KS_ * 64), dim3(64), 0, stream>>>(Whh_f, Whh_b, Bpack);
  k_lstm<<<dim3(512), dim3(512), 0, stream>>>(char_ids, word_lens, perm, ep4, Bpack, hcat);
  k_proj<<<dim3(NW / PM_), dim3(256), 0, stream>>>(hcat, pW, pb, out);
}